// Round 1
// baseline (189.792 us; speedup 1.0000x reference)
//
#include <hip/hip_runtime.h>
#include <hip/hip_bf16.h>

#define DIM 256
#define MEMN 512
#define TEMPF 10.0f

typedef float f32x4 __attribute__((ext_vector_type(4)));
typedef __bf16 bf16x8 __attribute__((ext_vector_type(8)));
typedef unsigned int u32;
typedef unsigned short u16;
typedef u32 u32x4 __attribute__((ext_vector_type(4)));

typedef __attribute__((address_space(1))) unsigned int as1_u32;
typedef __attribute__((address_space(3))) unsigned int as3_u32;

__device__ __forceinline__ void gll16(const void* gp, void* lp) {
  __builtin_amdgcn_global_load_lds((const as1_u32*)gp, (as3_u32*)lp, 16, 0, 0);
}

__device__ __forceinline__ u16 bf16bits(float x) {
  __bf16 h = (__bf16)x;
  return __builtin_bit_cast(u16, h);
}
__device__ __forceinline__ u32 pack2(float a, float b) {
  return (u32)bf16bits(a) | ((u32)bf16bits(b) << 16);
}

// KnFrag[kc][mt][lane][j] = Kn_norm[mt*16+(lane&15)][kc*32+(lane>>4)*8+j], kc<8, mt<32
// (A-operand fragment order for mfma_f32_16x16x32_bf16: A[l%16][(l/16)*8+j])
__global__ void prep_keys(const float* __restrict__ keys, u16* __restrict__ knf) {
  int lane = threadIdx.x & 63;
  int m = blockIdx.x * 4 + (threadIdx.x >> 6);   // one wave per key row
  float4 v = *reinterpret_cast<const float4*>(keys + (size_t)m * DIM + lane * 4);
  float ss = v.x*v.x + v.y*v.y + v.z*v.z + v.w*v.w;
  #pragma unroll
  for (int o = 1; o < 64; o <<= 1) ss += __shfl_xor(ss, o);
  float rn = 1.0f / fmaxf(sqrtf(ss), 1e-12f);
  float vals[4] = {v.x*rn, v.y*rn, v.z*rn, v.w*rn};
  int mt = m >> 4, ml = m & 15;
  #pragma unroll
  for (int t = 0; t < 4; ++t) {
    int d = lane * 4 + t;
    int kc = d >> 5, gg = (d >> 3) & 3, j = d & 7;
    knf[(size_t)((kc*32 + mt)*64 + gg*16 + ml)*8 + j] = bf16bits(vals[t]);
  }
}

// VtFrag[kc][dt][lane][j] = V[kc*32+(lane>>4)*8+j][dt*16+(lane&15)], kc<16, dt<16
__global__ void prep_vals(const float* __restrict__ mv, u16* __restrict__ vtf) {
  int lane = threadIdx.x & 63;
  int m = blockIdx.x * 4 + (threadIdx.x >> 6);
  float4 v = *reinterpret_cast<const float4*>(mv + (size_t)m * DIM + lane * 4);
  float vals[4] = {v.x, v.y, v.z, v.w};
  int kc = m >> 5, gg = (m >> 3) & 3, j = m & 7;
  #pragma unroll
  for (int t = 0; t < 4; ++t) {
    int d = lane * 4 + t;
    int dt = d >> 4, dl = d & 15;
    vtf[(size_t)((kc*16 + dt)*64 + gg*16 + dl)*8 + j] = bf16bits(vals[t]);
  }
}

// Main fused kernel. Block = 256 threads (4 waves), 64 query rows per block.
// Wave handles 16 rows. Lane (g = lane>>4, c = lane&15) owns query row c of its
// wave; its registers hold d-slices {32*kc + 8g + j}.
// GEMM1 computes S^T = mfma(A=KnFrag, B=Q): D-layout puts S^T[m][row c] in lane
// (g,c) as m = mt*16 + 4g + i -> full logit row is lane-local across {g}.
__global__ __launch_bounds__(256, 2) void fused_main(
    const float* __restrict__ q, const u16* __restrict__ knf,
    const u16* __restrict__ vtf, float* __restrict__ out_o,
    float* __restrict__ out_w, float* __restrict__ out_s) {
  __shared__ __align__(16) char lds[65536];  // GEMM1: 2x32KB Kn bufs; GEMM2: 2x16KB V bufs
  const int tid = threadIdx.x;
  const int wave = tid >> 6, lane = tid & 63;
  const int g = lane >> 4, c = lane & 15;
  const int row = blockIdx.x * 64 + wave * 16 + c;

  auto stage_k = [&](int kc, int buf) {
    const char* src = (const char*)knf + (size_t)kc * 32768;
    char* dst = lds + buf * 32768;
    #pragma unroll
    for (int i = 0; i < 8; ++i)
      gll16(src + i*4096 + tid*16, dst + i*4096 + wave*1024);  // wave-uniform LDS base
  };
  auto stage_v = [&](int kc, int buf) {
    const char* src = (const char*)vtf + (size_t)kc * 16384;
    char* dst = lds + buf * 16384;
    #pragma unroll
    for (int i = 0; i < 4; ++i)
      gll16(src + i*4096 + tid*16, dst + i*4096 + wave*1024);
  };

  // issue first two Kn chunk stages early (hide under Q load + scene + norm)
  stage_k(0, 0);
  stage_k(1, 1);

  // ---- load Q (fp32), fused scene-diff, L2-normalize, convert to bf16 frags ----
  float qv[64];
  const float* qrow = q + (size_t)row * DIM + g * 8;
  #pragma unroll
  for (int kc = 0; kc < 8; ++kc) {
    float4 a = *reinterpret_cast<const float4*>(qrow + kc * 32);
    float4 b = *reinterpret_cast<const float4*>(qrow + kc * 32 + 4);
    qv[kc*8+0]=a.x; qv[kc*8+1]=a.y; qv[kc*8+2]=a.z; qv[kc*8+3]=a.w;
    qv[kc*8+4]=b.x; qv[kc*8+5]=b.y; qv[kc*8+6]=b.z; qv[kc*8+7]=b.w;
  }
  float sd = 0.f, ss = 0.f;
  #pragma unroll
  for (int k = 0; k < 64; ++k) {
    float nb = __shfl_down(qv[k], 1);   // row c+1, same g, same d-slice (valid c<15)
    float d0 = nb - qv[k];
    sd += d0 * d0;
    ss += qv[k] * qv[k];
  }
  sd += __shfl_xor(sd, 16); sd += __shfl_xor(sd, 32);
  ss += __shfl_xor(ss, 16); ss += __shfl_xor(ss, 32);
  if (g == 0 && c < 15)                 // i%16==15 handled by scene_bound kernel
    out_s[row] = (sqrtf(sd) < 0.8f) ? 1.0f : 0.0f;
  float rn = 1.0f / fmaxf(sqrtf(ss), 1e-12f);
  bf16x8 qbf[8];
  #pragma unroll
  for (int kc = 0; kc < 8; ++kc) {
    #pragma unroll
    for (int j = 0; j < 8; ++j) qbf[kc][j] = (__bf16)(qv[kc*8+j] * rn);
  }

  // ---- GEMM1: S^T[512 x 16] = Kn[512x256] * Qn^T[256x16], K-chunks of 32 ----
  f32x4 acc[32];
  #pragma unroll
  for (int mt = 0; mt < 32; ++mt) { f32x4 z = {}; acc[mt] = z; }

  __syncthreads();
  #pragma unroll
  for (int kc = 0; kc < 8; ++kc) {
    const char* bufp = lds + (kc & 1) * 32768;
    #pragma unroll
    for (int mt = 0; mt < 32; ++mt) {
      bf16x8 af = *reinterpret_cast<const bf16x8*>(bufp + mt*1024 + lane*16);
      acc[mt] = __builtin_amdgcn_mfma_f32_16x16x32_bf16(af, qbf[kc], acc[mt], 0, 0, 0);
    }
    __syncthreads();
    if (kc < 6) stage_k(kc + 2, kc & 1);
  }

  // issue first V stages; softmax VALU work hides the latency
  stage_v(0, 0);
  stage_v(1, 1);

  // ---- softmax (no max-sub: |10*cos| <= 10, exp fits fp32 comfortably) ----
  float sum = 0.f;
  #pragma unroll
  for (int mt = 0; mt < 32; ++mt) {
    #pragma unroll
    for (int i = 0; i < 4; ++i) {
      float e = __expf(acc[mt][i] * TEMPF);
      acc[mt][i] = e;
      sum += e;
    }
  }
  sum += __shfl_xor(sum, 16); sum += __shfl_xor(sum, 32);
  float rcp = 1.0f / sum;

  // weights out (float4, contiguous per row) + pack exp to bf16 pairs for GEMM2
  u32 hpair[64];                         // hpair[mt*2+s] = bf16x2(e[m], e[m+1]), m = mt*16+4g+2s
  float* wrow = out_w + (size_t)row * MEMN + g * 4;
  #pragma unroll
  for (int mt = 0; mt < 32; ++mt) {
    float4 wv = { acc[mt][0]*rcp, acc[mt][1]*rcp, acc[mt][2]*rcp, acc[mt][3]*rcp };
    *reinterpret_cast<float4*>(wrow + mt * 16) = wv;
    hpair[mt*2+0] = pack2(acc[mt][0], acc[mt][1]);
    hpair[mt*2+1] = pack2(acc[mt][2], acc[mt][3]);
  }

  // ---- GEMM2: O^T[256 x 16] = V^T[256x512] * W^T[512x16] ----
  // B-frag lane (g,c) needs W^T pairs pp = 16*kc + 4g + p' (p'=0..3) of row c.
  // Held: pair pp at lane g2=(pp&7)>>1 (same c), reg hpair[(pp>>3)*2 + (pp&1)].
  // -> 2 bpermutes (mt=2kc vs 2kc+1) + select on g>=2, per dword.
  f32x4 oacc[16];
  #pragma unroll
  for (int dt = 0; dt < 16; ++dt) { f32x4 z = {}; oacc[dt] = z; }

  const int addrA = ((2*(g&1) + 0)*16 + c) * 4;   // src lane for p'=0,1
  const int addrB = ((2*(g&1) + 1)*16 + c) * 4;   // src lane for p'=2,3
  const bool hig = (g >= 2);

  __syncthreads();
  #pragma unroll
  for (int kc = 0; kc < 16; ++kc) {
    const char* bufp = lds + (kc & 1) * 16384;
    u32x4 wf;
    {
      int v1 = __builtin_amdgcn_ds_bpermute(addrA, (int)hpair[4*kc+0]);
      int v2 = __builtin_amdgcn_ds_bpermute(addrA, (int)hpair[4*kc+2]);
      wf[0] = (u32)(hig ? v2 : v1);
      v1 = __builtin_amdgcn_ds_bpermute(addrA, (int)hpair[4*kc+1]);
      v2 = __builtin_amdgcn_ds_bpermute(addrA, (int)hpair[4*kc+3]);
      wf[1] = (u32)(hig ? v2 : v1);
      v1 = __builtin_amdgcn_ds_bpermute(addrB, (int)hpair[4*kc+0]);
      v2 = __builtin_amdgcn_ds_bpermute(addrB, (int)hpair[4*kc+2]);
      wf[2] = (u32)(hig ? v2 : v1);
      v1 = __builtin_amdgcn_ds_bpermute(addrB, (int)hpair[4*kc+1]);
      v2 = __builtin_amdgcn_ds_bpermute(addrB, (int)hpair[4*kc+3]);
      wf[3] = (u32)(hig ? v2 : v1);
    }
    bf16x8 bfrag = __builtin_bit_cast(bf16x8, wf);
    #pragma unroll
    for (int dt = 0; dt < 16; ++dt) {
      bf16x8 af = *reinterpret_cast<const bf16x8*>(bufp + dt*1024 + lane*16);
      oacc[dt] = __builtin_amdgcn_mfma_f32_16x16x32_bf16(af, bfrag, oacc[dt], 0, 0, 0);
    }
    __syncthreads();
    if (kc < 14) stage_v(kc + 2, kc & 1);
  }

  // ---- store O (scaled by 1/sum; rcp is lane-local for row c) ----
  float* orow = out_o + (size_t)row * DIM + g * 4;
  #pragma unroll
  for (int dt = 0; dt < 16; ++dt) {
    float4 ov = { oacc[dt][0]*rcp, oacc[dt][1]*rcp, oacc[dt][2]*rcp, oacc[dt][3]*rcp };
    *reinterpret_cast<float4*>(orow + dt * 16) = ov;
  }
}

// Boundary scene diffs: i % 16 == 15 (one wave per i)
__global__ void scene_bound(const float* __restrict__ q, float* __restrict__ out_s, int B) {
  int widx = (blockIdx.x * blockDim.x + threadIdx.x) >> 6;
  int lane = threadIdx.x & 63;
  int i = widx * 16 + 15;
  if (i > B - 2) return;
  const float* a = q + (size_t)i * DIM + lane * 4;
  float4 x = *reinterpret_cast<const float4*>(a);
  float4 y = *reinterpret_cast<const float4*>(a + DIM);
  float dx = y.x-x.x, dy = y.y-x.y, dz = y.z-x.z, dw = y.w-x.w;
  float sd = dx*dx + dy*dy + dz*dz + dw*dw;
  #pragma unroll
  for (int o = 1; o < 64; o <<= 1) sd += __shfl_xor(sd, o);
  if (lane == 0) out_s[i] = (sqrtf(sd) < 0.8f) ? 1.0f : 0.0f;
}

extern "C" void kernel_launch(void* const* d_in, const int* in_sizes, int n_in,
                              void* d_out, int out_size, void* d_ws, size_t ws_size,
                              hipStream_t stream) {
  const float* q  = (const float*)d_in[0];
  const float* mk = (const float*)d_in[1];
  const float* mv = (const float*)d_in[2];
  int B = in_sizes[0] / DIM;            // 131072
  float* o = (float*)d_out;
  float* w = o + (size_t)B * DIM;
  float* s = w + (size_t)B * MEMN;
  u16* knf = (u16*)d_ws;                         // 256 KB
  u16* vtf = (u16*)((char*)d_ws + 262144);       // 256 KB
  prep_keys<<<128, 256, 0, stream>>>(mk, knf);
  prep_vals<<<128, 256, 0, stream>>>(mv, vtf);
  fused_main<<<B / 64, 256, 0, stream>>>(q, knf, vtf, o, w, s);
  int nwaves = B / 16;
  scene_bound<<<(nwaves + 3) / 4, 256, 0, stream>>>(q, s, B);
}